// Round 6
// baseline (125.348 us; speedup 1.0000x reference)
//
#include <hip/hip_runtime.h>
#include <math.h>

#define NSEG 20001      // I_DIM + 1 segments / items
#define EMB  128
#define NE   640000

#define SCALE_BLOCKS 313         // ceil(NSEG/64)
#define BOUNDS_BLOCKS 2500       // NE/256 exact
#define LDSL 129                 // padded row stride (floats): 2-way bank aliasing only

__device__ __forceinline__ float dot4(float4 a, float4 b) {
    return a.x*b.x + a.y*b.y + a.z*b.z + a.w*b.w;
}

#define FMA4(acc, s, b) { acc.x += (s)*(b).x; acc.y += (s)*(b).y; acc.z += (s)*(b).z; acc.w += (s)*(b).w; }

__device__ __forceinline__ unsigned f2bf(float x) {
    unsigned u = __float_as_uint(x);
    return (u + 0x7fffu + ((u >> 16) & 1u)) >> 16;   // round-nearest-even
}

// Fused prep (unchanged from R4 — proven):
//  blocks [0, SCALE_BLOCKS): item_scaled(bf16 tab) + a_src/a_dst.
//  blocks [SCALE_BLOCKS, +BOUNDS_BLOCKS): segment bounds + dst compaction.
__global__ __launch_bounds__(256) void prep_kernel(
    const float* __restrict__ emb, const float* __restrict__ W,
    const float* __restrict__ bsc, const float* __restrict__ Watt,
    const int* __restrict__ edge,
    unsigned short* __restrict__ tab,       // bf16 item_scaled, NSEG x EMB
    float* __restrict__ a_src, float* __restrict__ a_dst,
    int* __restrict__ seg_start, int* __restrict__ dst)
{
    const int tid = threadIdx.x;
    if (blockIdx.x >= SCALE_BLOCKS) {
        // ---- bounds + dst-compaction ----
        int e = (blockIdx.x - SCALE_BLOCKS) * 256 + tid;
        int2 p = ((const int2*)edge)[e];            // coalesced 8B
        dst[e] = p.y;
        int sp = __shfl_up(p.x, 1);
        if ((tid & 63) == 0) sp = (e == 0) ? -1 : edge[2*e - 2];
        for (int t = sp + 1; t <= p.x; ++t) seg_start[t] = e;
        if (e == NE - 1) {
            for (int t = p.x + 1; t <= NSEG; ++t) seg_start[t] = NE;
        }
        return;
    }

    // ---- scale branch: 64 rows/block; thread = (cg: 8 cols) x (4 rows) ----
    __shared__ float emb_s[64 * LDSL];   // 33 KB
    const int r0 = blockIdx.x * 64;

    const float4* embg4 = (const float4*)emb;
    const int gmax = NSEG * 32 - 1;
    #pragma unroll
    for (int j = 0; j < 8; ++j) {
        int idx = tid + j * 256;            // 0..2047 tile float4 slots
        int row = idx >> 5, f4 = idx & 31;
        int g = r0 * 32 + idx;
        float4 v = embg4[g <= gmax ? g : gmax];
        float* p = &emb_s[row * LDSL + f4 * 4];
        p[0] = v.x; p[1] = v.y; p[2] = v.z; p[3] = v.w;
    }
    __syncthreads();

    const int cg   = tid & 15;            // cols [8cg, 8cg+8)
    const int rowb = (tid >> 4) * 4;      // 4 rows per thread

    float4 accA[4] = {{0,0,0,0},{0,0,0,0},{0,0,0,0},{0,0,0,0}};
    float4 accB[4] = {{0,0,0,0},{0,0,0,0},{0,0,0,0},{0,0,0,0}};
    const float4* Wg4 = (const float4*)W;

    #pragma unroll 4
    for (int k = 0; k < EMB; ++k) {
        float4 w0 = Wg4[k*32 + cg*2];
        float4 w1 = Wg4[k*32 + cg*2 + 1];
        float a0 = emb_s[(rowb+0)*LDSL + k];
        float a1 = emb_s[(rowb+1)*LDSL + k];
        float a2 = emb_s[(rowb+2)*LDSL + k];
        float a3 = emb_s[(rowb+3)*LDSL + k];
        FMA4(accA[0], a0, w0); FMA4(accB[0], a0, w1);
        FMA4(accA[1], a1, w0); FMA4(accB[1], a1, w1);
        FMA4(accA[2], a2, w0); FMA4(accB[2], a2, w1);
        FMA4(accA[3], a3, w0); FMA4(accB[3], a3, w1);
    }

    const float4 bsA = *(const float4*)&bsc[cg*8];
    const float4 bsB = *(const float4*)&bsc[cg*8 + 4];
    const float4 wsA = *(const float4*)&Watt[cg*8];
    const float4 wsB = *(const float4*)&Watt[cg*8 + 4];
    const float4 wdA = *(const float4*)&Watt[EMB + cg*8];
    const float4 wdB = *(const float4*)&Watt[EMB + cg*8 + 4];

    #pragma unroll
    for (int r = 0; r < 4; ++r) {
        float4 A = accA[r], B = accB[r];
        A.x += bsA.x; A.y += bsA.y; A.z += bsA.z; A.w += bsA.w;
        B.x += bsB.x; B.y += bsB.y; B.z += bsB.z; B.w += bsB.w;
        const int row = r0 + rowb + r;

        if (row < NSEG) {
            uint4 pkt;
            pkt.x = f2bf(A.x) | (f2bf(A.y) << 16);
            pkt.y = f2bf(A.z) | (f2bf(A.w) << 16);
            pkt.z = f2bf(B.x) | (f2bf(B.y) << 16);
            pkt.w = f2bf(B.z) | (f2bf(B.w) << 16);
            ((uint4*)tab)[row * 16 + cg] = pkt;
        }

        float ps = dot4(A, wsA) + dot4(B, wsB);
        float pd = dot4(A, wdA) + dot4(B, wdB);
        #pragma unroll
        for (int off = 8; off >= 1; off >>= 1) {
            ps += __shfl_xor(ps, off);
            pd += __shfl_xor(pd, off);
        }
        if (cg == 0 && row < NSEG) { a_src[row] = ps; a_dst[row] = pd; }
    }
}

__device__ __forceinline__ float bf_lo(unsigned u) { return __uint_as_float(u << 16); }
__device__ __forceinline__ float bf_hi(unsigned u) { return __uint_as_float(u & 0xffff0000u); }
__device__ __forceinline__ float bcastf(float v, int j) {
    return __uint_as_float(__builtin_amdgcn_readlane(__float_as_uint(v), j));
}

// agg v3: feature-half split keyed to blockIdx parity (XCD L2 locality).
//   block = 4 waves = 4 segments; half = blockIdx & 1 selects features
//   [half*64, half*64+64) == dwords [half*32, +32) of each 64-dword row.
//   Even blocks -> XCDs {0,2,4,6} (round-robin heuristic) touch only half 0
//   (2.56 MB, fully L2-resident per XCD); odd blocks half 1.
//   Lane l: sub = l>>5 selects edge j+sub of a pair; dw = l&31 the dword.
//   2 edges per load instruction; scores computed redundantly in both halves.
__global__ __launch_bounds__(256) void agg_kernel(
    const int* __restrict__ dst, const float* __restrict__ a_src,
    const float* __restrict__ a_dst, const float* __restrict__ b_att,
    const int* __restrict__ seg_start, const unsigned int* __restrict__ tab32,
    float* __restrict__ out)
{
    const int half = blockIdx.x & 1;
    const int wid  = (blockIdx.x >> 1) * 4 + (threadIdx.x >> 6);
    if (wid >= NSEG) return;                 // wave-uniform exit
    const int lane = threadIdx.x & 63;
    const int sub  = lane >> 5;              // edge-in-pair
    const int dw   = lane & 31;              // dword within half-row
    const unsigned int* tabl = tab32 + half * 32 + dw;

    const int s0 = seg_start[wid];
    const int s1 = seg_start[wid + 1];
    const float aS = a_src[wid] + b_att[0];

    float accx = 0.f, accy = 0.f, ssum = 0.f;

    for (int cb = s0; cb < s1; cb += 64) {
        int n = s1 - cb; if (n > 64) n = 64;
        int e = cb + lane;
        int dmine = 0; float sc = 0.f;
        if (lane < n) {
            dmine = dst[e] << 6;             // pre-scaled dword row offset
            float att = aS + a_dst[dmine >> 6];
            att = att > 0.f ? att : 0.2f * att;   // leaky_relu 0.2
            sc  = expf(att - 1.f);
        }
        ssum += sc;

        int j = 0;
        // 8 pairs unrolled = 16 edges, 8 outstanding loads
        for (; j + 15 < n; j += 16) {
            #pragma unroll
            for (int p = 0; p < 8; ++p) {
                float wa = bcastf(sc, j + 2*p);
                float wb = bcastf(sc, j + 2*p + 1);
                int   da = __builtin_amdgcn_readlane(dmine, j + 2*p);
                int   db = __builtin_amdgcn_readlane(dmine, j + 2*p + 1);
                float w = sub ? wb : wa;
                int   d = sub ? db : da;
                unsigned u = tabl[d];
                accx += w * bf_lo(u);
                accy += w * bf_hi(u);
            }
        }
        for (; j < n; j += 2) {
            float wa = bcastf(sc, j);
            int   da = __builtin_amdgcn_readlane(dmine, j);
            float wb = 0.f; int db = da;
            if (j + 1 < n) {                 // wave-uniform
                wb = bcastf(sc, j + 1);
                db = __builtin_amdgcn_readlane(dmine, j + 1);
            }
            float w = sub ? wb : wa;
            int   d = sub ? db : da;
            unsigned u = tabl[d];
            accx += w * bf_lo(u);
            accy += w * bf_hi(u);
        }
    }

    // segment score sum (each lane held distinct edges' scores)
    #pragma unroll
    for (int off = 32; off >= 1; off >>= 1) ssum += __shfl_xor(ssum, off);

    // combine the two edge-subsets (lanes l and l+32 share a feature dword)
    accx += __shfl_xor(accx, 32);
    accy += __shfl_xor(accy, 32);

    const float inv = (s1 > s0) ? 1.f / ssum : 0.f;
    if (lane < 32) {
        float ox = 1.f / (1.f + expf(-accx * inv));
        float oy = 1.f / (1.f + expf(-accy * inv));
        *(float2*)&out[wid * EMB + half * 64 + 2 * dw] = make_float2(ox, oy);
    }
}

extern "C" void kernel_launch(void* const* d_in, const int* in_sizes, int n_in,
                              void* d_out, int out_size, void* d_ws, size_t ws_size,
                              hipStream_t stream) {
    const float* emb  = (const float*)d_in[0];   // (20001, 128)
    const int*   edge = (const int*)  d_in[1];   // (640000, 2)
    const float* W    = (const float*)d_in[2];   // (128, 128)
    const float* bsc  = (const float*)d_in[3];   // (128,)
    const float* Watt = (const float*)d_in[4];   // (256,)
    const float* batt = (const float*)d_in[5];   // (1,)
    float* out = (float*)d_out;                  // (20001, 128)

    unsigned short* tab = (unsigned short*)d_ws;            // NSEG*EMB bf16 (5.12 MB)
    float* a_src = (float*)(tab + (size_t)NSEG * EMB);      // NSEG
    float* a_dst = a_src + NSEG;                            // NSEG
    int*   seg_start = (int*)(a_dst + NSEG);                // NSEG+1
    int*   dstc = seg_start + NSEG + 3;                     // NE (compacted dst col)

    prep_kernel<<<SCALE_BLOCKS + BOUNDS_BLOCKS, 256, 0, stream>>>(
        emb, W, bsc, Watt, edge, tab, a_src, a_dst, seg_start, dstc);
    agg_kernel<<<2 * ((NSEG + 3) / 4), 256, 0, stream>>>(
        dstc, a_src, a_dst, batt, seg_start, (const unsigned int*)tab, out);
}

// Round 7
// 112.591 us; speedup vs baseline: 1.1133x; 1.1133x over previous
//
#include <hip/hip_runtime.h>
#include <math.h>

#define NSEG 20001      // I_DIM + 1 segments / items
#define EMB  128
#define NE   640000

#define SCALE_BLOCKS 313         // ceil(NSEG/64)
#define BOUNDS_BLOCKS 2500       // NE/256 exact
#define LDSL 129                 // padded row stride (floats): 2-way bank aliasing only

__device__ __forceinline__ float dot4(float4 a, float4 b) {
    return a.x*b.x + a.y*b.y + a.z*b.z + a.w*b.w;
}

#define FMA4(acc, s, b) { acc.x += (s)*(b).x; acc.y += (s)*(b).y; acc.z += (s)*(b).z; acc.w += (s)*(b).w; }

__device__ __forceinline__ unsigned f2bf(float x) {
    unsigned u = __float_as_uint(x);
    return (u + 0x7fffu + ((u >> 16) & 1u)) >> 16;   // round-nearest-even
}

// Fused prep (R4 — proven):
//  blocks [0, SCALE_BLOCKS): item_scaled(bf16 tab) + a_src/a_dst.
//  blocks [SCALE_BLOCKS, +BOUNDS_BLOCKS): segment bounds + dst compaction.
__global__ __launch_bounds__(256) void prep_kernel(
    const float* __restrict__ emb, const float* __restrict__ W,
    const float* __restrict__ bsc, const float* __restrict__ Watt,
    const int* __restrict__ edge,
    unsigned short* __restrict__ tab,       // bf16 item_scaled, NSEG x EMB
    float* __restrict__ a_src, float* __restrict__ a_dst,
    int* __restrict__ seg_start, int* __restrict__ dst)
{
    const int tid = threadIdx.x;
    if (blockIdx.x >= SCALE_BLOCKS) {
        // ---- bounds + dst-compaction ----
        int e = (blockIdx.x - SCALE_BLOCKS) * 256 + tid;
        int2 p = ((const int2*)edge)[e];            // coalesced 8B
        dst[e] = p.y;
        int sp = __shfl_up(p.x, 1);
        if ((tid & 63) == 0) sp = (e == 0) ? -1 : edge[2*e - 2];
        for (int t = sp + 1; t <= p.x; ++t) seg_start[t] = e;
        if (e == NE - 1) {
            for (int t = p.x + 1; t <= NSEG; ++t) seg_start[t] = NE;
        }
        return;
    }

    // ---- scale branch: 64 rows/block; thread = (cg: 8 cols) x (4 rows) ----
    __shared__ float emb_s[64 * LDSL];   // 33 KB
    const int r0 = blockIdx.x * 64;

    const float4* embg4 = (const float4*)emb;
    const int gmax = NSEG * 32 - 1;
    #pragma unroll
    for (int j = 0; j < 8; ++j) {
        int idx = tid + j * 256;            // 0..2047 tile float4 slots
        int row = idx >> 5, f4 = idx & 31;
        int g = r0 * 32 + idx;
        float4 v = embg4[g <= gmax ? g : gmax];
        float* p = &emb_s[row * LDSL + f4 * 4];
        p[0] = v.x; p[1] = v.y; p[2] = v.z; p[3] = v.w;
    }
    __syncthreads();

    const int cg   = tid & 15;            // cols [8cg, 8cg+8)
    const int rowb = (tid >> 4) * 4;      // 4 rows per thread

    float4 accA[4] = {{0,0,0,0},{0,0,0,0},{0,0,0,0},{0,0,0,0}};
    float4 accB[4] = {{0,0,0,0},{0,0,0,0},{0,0,0,0},{0,0,0,0}};
    const float4* Wg4 = (const float4*)W;

    #pragma unroll 4
    for (int k = 0; k < EMB; ++k) {
        float4 w0 = Wg4[k*32 + cg*2];
        float4 w1 = Wg4[k*32 + cg*2 + 1];
        float a0 = emb_s[(rowb+0)*LDSL + k];
        float a1 = emb_s[(rowb+1)*LDSL + k];
        float a2 = emb_s[(rowb+2)*LDSL + k];
        float a3 = emb_s[(rowb+3)*LDSL + k];
        FMA4(accA[0], a0, w0); FMA4(accB[0], a0, w1);
        FMA4(accA[1], a1, w0); FMA4(accB[1], a1, w1);
        FMA4(accA[2], a2, w0); FMA4(accB[2], a2, w1);
        FMA4(accA[3], a3, w0); FMA4(accB[3], a3, w1);
    }

    const float4 bsA = *(const float4*)&bsc[cg*8];
    const float4 bsB = *(const float4*)&bsc[cg*8 + 4];
    const float4 wsA = *(const float4*)&Watt[cg*8];
    const float4 wsB = *(const float4*)&Watt[cg*8 + 4];
    const float4 wdA = *(const float4*)&Watt[EMB + cg*8];
    const float4 wdB = *(const float4*)&Watt[EMB + cg*8 + 4];

    #pragma unroll
    for (int r = 0; r < 4; ++r) {
        float4 A = accA[r], B = accB[r];
        A.x += bsA.x; A.y += bsA.y; A.z += bsA.z; A.w += bsA.w;
        B.x += bsB.x; B.y += bsB.y; B.z += bsB.z; B.w += bsB.w;
        const int row = r0 + rowb + r;

        if (row < NSEG) {
            uint4 pkt;
            pkt.x = f2bf(A.x) | (f2bf(A.y) << 16);
            pkt.y = f2bf(A.z) | (f2bf(A.w) << 16);
            pkt.z = f2bf(B.x) | (f2bf(B.y) << 16);
            pkt.w = f2bf(B.z) | (f2bf(B.w) << 16);
            ((uint4*)tab)[row * 16 + cg] = pkt;
        }

        float ps = dot4(A, wsA) + dot4(B, wsB);
        float pd = dot4(A, wdA) + dot4(B, wdB);
        #pragma unroll
        for (int off = 8; off >= 1; off >>= 1) {
            ps += __shfl_xor(ps, off);
            pd += __shfl_xor(pd, off);
        }
        if (cg == 0 && row < NSEG) { a_src[row] = ps; a_dst[row] = pd; }
    }
}

__device__ __forceinline__ float bf_lo(unsigned u) { return __uint_as_float(u << 16); }
__device__ __forceinline__ float bf_hi(unsigned u) { return __uint_as_float(u & 0xffff0000u); }
__device__ __forceinline__ float bcastf(float v, int j) {
    return __uint_as_float(__builtin_amdgcn_readlane(__float_as_uint(v), j));
}

// agg (R4 structure, unroll-16): one wave per segment; lane l owns features
// {2l, 2l+1} (one bf16x2 dword). 16 outstanding gathers per batch.
__global__ __launch_bounds__(256) void agg_kernel(
    const int* __restrict__ dst, const float* __restrict__ a_src,
    const float* __restrict__ a_dst, const float* __restrict__ b_att,
    const int* __restrict__ seg_start, const unsigned int* __restrict__ tab32,
    float* __restrict__ out)
{
    const int wid = blockIdx.x * 4 + (threadIdx.x >> 6);
    if (wid >= NSEG) return;                 // wave-uniform exit
    const int lane = threadIdx.x & 63;
    const unsigned int* tabl = tab32 + lane; // row stride 64 dwords

    const int s0 = seg_start[wid];
    const int s1 = seg_start[wid + 1];
    const float aS = a_src[wid] + b_att[0];

    float accx = 0.f, accy = 0.f, ssum = 0.f;

    for (int cb = s0; cb < s1; cb += 64) {
        int n = s1 - cb; if (n > 64) n = 64;
        int e = cb + lane;
        int dmine = 0; float sc = 0.f;
        if (lane < n) {
            dmine = dst[e] << 6;             // pre-scaled dword row offset
            float att = aS + a_dst[dmine >> 6];
            att = att > 0.f ? att : 0.2f * att;   // leaky_relu 0.2
            sc  = expf(att - 1.f);
        }
        ssum += sc;

        int j = 0;
        for (; j + 15 < n; j += 16) {
            float w[16]; int d[16]; unsigned u[16];
            #pragma unroll
            for (int p = 0; p < 16; ++p) {
                w[p] = bcastf(sc, j + p);
                d[p] = __builtin_amdgcn_readlane(dmine, j + p);
            }
            #pragma unroll
            for (int p = 0; p < 16; ++p) u[p] = tabl[d[p]];
            #pragma unroll
            for (int p = 0; p < 16; ++p) {
                accx += w[p] * bf_lo(u[p]);
                accy += w[p] * bf_hi(u[p]);
            }
        }
        for (; j + 7 < n; j += 8) {
            float w[8]; int d[8]; unsigned u[8];
            #pragma unroll
            for (int p = 0; p < 8; ++p) {
                w[p] = bcastf(sc, j + p);
                d[p] = __builtin_amdgcn_readlane(dmine, j + p);
            }
            #pragma unroll
            for (int p = 0; p < 8; ++p) u[p] = tabl[d[p]];
            #pragma unroll
            for (int p = 0; p < 8; ++p) {
                accx += w[p] * bf_lo(u[p]);
                accy += w[p] * bf_hi(u[p]);
            }
        }
        for (; j < n; ++j) {
            float w = bcastf(sc, j);
            int   d = __builtin_amdgcn_readlane(dmine, j);
            unsigned u = tabl[d];
            accx += w * bf_lo(u);
            accy += w * bf_hi(u);
        }
    }

    #pragma unroll
    for (int off = 32; off >= 1; off >>= 1) ssum += __shfl_xor(ssum, off);

    const float inv = (s1 > s0) ? 1.f / ssum : 0.f;
    float ox = accx * inv, oy = accy * inv;
    ox = 1.f / (1.f + expf(-ox));
    oy = 1.f / (1.f + expf(-oy));
    *(float2*)&out[wid * EMB + 2 * lane] = make_float2(ox, oy);
}

extern "C" void kernel_launch(void* const* d_in, const int* in_sizes, int n_in,
                              void* d_out, int out_size, void* d_ws, size_t ws_size,
                              hipStream_t stream) {
    const float* emb  = (const float*)d_in[0];   // (20001, 128)
    const int*   edge = (const int*)  d_in[1];   // (640000, 2)
    const float* W    = (const float*)d_in[2];   // (128, 128)
    const float* bsc  = (const float*)d_in[3];   // (128,)
    const float* Watt = (const float*)d_in[4];   // (256,)
    const float* batt = (const float*)d_in[5];   // (1,)
    float* out = (float*)d_out;                  // (20001, 128)

    unsigned short* tab = (unsigned short*)d_ws;            // NSEG*EMB bf16 (5.12 MB)
    float* a_src = (float*)(tab + (size_t)NSEG * EMB);      // NSEG
    float* a_dst = a_src + NSEG;                            // NSEG
    int*   seg_start = (int*)(a_dst + NSEG);                // NSEG+1
    int*   dstc = seg_start + NSEG + 3;                     // NE (compacted dst col)

    prep_kernel<<<SCALE_BLOCKS + BOUNDS_BLOCKS, 256, 0, stream>>>(
        emb, W, bsc, Watt, edge, tab, a_src, a_dst, seg_start, dstc);
    agg_kernel<<<(NSEG + 3) / 4, 256, 0, stream>>>(
        dstc, a_src, a_dst, batt, seg_start, (const unsigned int*)tab, out);
}